// Round 13
// baseline (161.199 us; speedup 1.0000x reference)
//
#include <hip/hip_runtime.h>
#include <math.h>

// CrossAttention: B=4, N=2048, M=1024, HEADS=16, DHEAD=64, model dim 1024.
// fused preprocessing (x-cvt + ctx-cvt + weight transpose in ONE launch);
// merged QKV GEMM and out GEMM BOTH on the 8-phase 256x128 template
// (register-held B quadrants, counted vmcnt(4)/(5) -- the faster measured
// sibling at ~690 TF); flash attention (8-warp QBLK=256, KVBLK=128,
// defer-max softmax per 64-row subtile, dbuf K/V, XCD-affinity swizzle,
// L-sum via MFMA ones-trick, raw v_exp_f32, permlane32_swap pack).

#define HEADS 16
#define DHEAD 64
#define DM    1024
#define BQ    4
#define NQ    2048
#define MK    1024

typedef unsigned short u16;
typedef __attribute__((ext_vector_type(8))) short bf16x8;
typedef __attribute__((ext_vector_type(2))) float f32x2;
typedef __attribute__((ext_vector_type(4))) float f32x4;
typedef __attribute__((ext_vector_type(16))) float f32x16;

__device__ __forceinline__ u16 f2bf(float f) {
  unsigned u = __builtin_bit_cast(unsigned, f);
  u = u + 0x7FFFu + ((u >> 16) & 1u);   // round-to-nearest-even
  return (u16)(u >> 16);
}

// packed bf16 word via HW cvt: low half <- %1, high half <- %2
__device__ __forceinline__ unsigned cvtpk(float lo, float hi2) {
  unsigned r;
  asm("v_cvt_pk_bf16_f32 %0, %1, %2" : "=v"(r) : "v"(lo), "v"(hi2));
  return r;
}

__device__ __forceinline__ float max3f(float a, float b, float c) {
  float d;
  asm("v_max3_f32 %0, %1, %2, %3" : "=v"(d) : "v"(a), "v"(b), "v"(c));
  return d;
}

// raw HW exp2 (skips libm fixup path)
__device__ __forceinline__ float fexp2(float x) {
  float r;
  asm("v_exp_f32 %0, %1" : "=v"(r) : "v"(x));
  return r;
}

// packed f32 ops (VOP3P, full-rate on CDNA2+)
__device__ __forceinline__ f32x2 pk_add(f32x2 a, f32x2 b) {
  f32x2 d;
  asm("v_pk_add_f32 %0, %1, %2" : "=v"(d) : "v"(a), "v"(b));
  return d;
}
__device__ __forceinline__ f32x2 pk_mul(f32x2 a, f32x2 b) {
  f32x2 d;
  asm("v_pk_mul_f32 %0, %1, %2" : "=v"(d) : "v"(a), "v"(b));
  return d;
}

// async global->LDS, 16B per lane; LDS dst = wave-uniform base + lane*16
__device__ __forceinline__ void gld16(const u16* g, u16* l) {
  __builtin_amdgcn_global_load_lds((const __attribute__((address_space(1))) void*)g,
                                   (__attribute__((address_space(3))) void*)l,
                                   16, 0, 0);
}

// ---------------- fused preprocessing: cvt(x) + cvt(ctx) + transpose(W) ----
// grid 10240 x 256 threads:
//   [0,4096)      x fp32 -> bf16, 8 elems/thread (n8 = 1048576)
//   [4096,6144)   ctx fp32 -> bf16 (n8 = 524288)
//   [6144,10240)  W[k][n] -> Wt[n][k] bf16, 32x32 tiles, 4 weights
__global__ void k_pre(const float* __restrict__ x, const float* __restrict__ ctx,
                      const float* __restrict__ W0, const float* __restrict__ W1,
                      const float* __restrict__ W2, const float* __restrict__ W3,
                      u16* __restrict__ xb, u16* __restrict__ cb,
                      u16* __restrict__ wt) {
  __shared__ float tsh[32][33];
  int blk = blockIdx.x, t = threadIdx.x;
  if (blk < 6144) {
    const float* in; u16* out; int i;
    if (blk < 4096) { in = x;   out = xb; i = blk * 256 + t; }
    else            { in = ctx; out = cb; i = (blk - 4096) * 256 + t; }
    float4 a = ((const float4*)in)[i * 2];
    float4 b = ((const float4*)in)[i * 2 + 1];
    union { u16 h[8]; int4 v; } r;
    r.h[0] = f2bf(a.x); r.h[1] = f2bf(a.y); r.h[2] = f2bf(a.z); r.h[3] = f2bf(a.w);
    r.h[4] = f2bf(b.x); r.h[5] = f2bf(b.y); r.h[6] = f2bf(b.z); r.h[7] = f2bf(b.w);
    ((int4*)out)[i] = r.v;
    return;
  }
  int vb = blk - 6144;                 // 4096 transpose tiles
  int z = vb >> 10, rem = vb & 1023;
  int by = rem >> 5, bx = rem & 31;
  const float* W = z == 0 ? W0 : z == 1 ? W1 : z == 2 ? W2 : W3;
  u16* o = wt + (size_t)z * DM * DM;
  int r0 = by * 32, c0 = bx * 32;
  int tx = t & 31, ty = t >> 5;
  for (int i = ty; i < 32; i += 8) tsh[i][tx] = W[(size_t)(r0 + i) * DM + c0 + tx];
  __syncthreads();
  for (int i = ty; i < 32; i += 8) o[(size_t)(c0 + i) * DM + r0 + tx] = f2bf(tsh[tx][i]);
}

// ============ 8-phase 256x128 GEMM core (BK=64, quadrant-per-phase) ========
// Quadrants 128(M) x 64(N); 8 waves as 4Mx2N (32x32/wave). B quadrant frags
// register-held (bfA=qn0, bfB=qn1) so ph4 is a pure-MFMA phase. Stage map:
//   ph1: B0(u+1)[1]  ph2: A1(u+1)[2]  ph3: A0(u+2)[2]  ph4: B1(u+2)[1]
// vmcnt(4) at ph1 (forces A1(u)); vmcnt(5) at ph4 (forces A0/B0/B1(u+1)).
// LDS swizzle: 16B-unit ^= (row&7), both-sides (rule #21). 96 KB LDS.
#define OSTG_A(bufi, h, kof) do {                                            \
  gld16(gA + (size_t)(h) * 131072 + (kof), &As8[bufi][(h) * 8192 + w * 512]); \
  gld16(gA + (size_t)(h) * 131072 + 65536 + (kof),                           \
        &As8[bufi][(h) * 8192 + 4096 + w * 512]);                            \
} while (0)

#define OSTG_B(bufi, h, kof)                                                 \
  gld16(gB + (size_t)(h) * 65536 + (kof), &Bs8[bufi][(h) * 4096 + w * 512])

#define ORD_A(qm) do { _Pragma("unroll")                                     \
  for (int mi = 0; mi < 2; ++mi) {                                           \
    const u16* pa = &As8[cur][((qm) * 128 + wmo + mi * 16 + lrow) * 64];     \
    af[mi][0] = *(const bf16x8*)(pa + fo0);                                  \
    af[mi][1] = *(const bf16x8*)(pa + (fo0 ^ 32));                           \
  } } while (0)

#define ORD_B(qn, dst) do { _Pragma("unroll")                                \
  for (int ni = 0; ni < 2; ++ni) {                                           \
    const u16* pb = &Bs8[cur][((qn) * 64 + wno + ni * 16 + lrow) * 64];      \
    dst[ni][0] = *(const bf16x8*)(pb + fo0);                                 \
    dst[ni][1] = *(const bf16x8*)(pb + (fo0 ^ 32));                          \
  } } while (0)

#define OMM(qm, qn, bfq) do {                                                \
  __builtin_amdgcn_s_setprio(1);                                             \
  _Pragma("unroll")                                                          \
  for (int mi = 0; mi < 2; ++mi)                                             \
    _Pragma("unroll")                                                        \
    for (int ni = 0; ni < 2; ++ni) {                                         \
      acc[qm][qn][mi][ni] = __builtin_amdgcn_mfma_f32_16x16x32_bf16(         \
          af[mi][0], bfq[ni][0], acc[qm][qn][mi][ni], 0, 0, 0);              \
      acc[qm][qn][mi][ni] = __builtin_amdgcn_mfma_f32_16x16x32_bf16(         \
          af[mi][1], bfq[ni][1], acc[qm][qn][mi][ni], 0, 0, 0);              \
    }                                                                        \
  __builtin_amdgcn_s_setprio(0);                                             \
} while (0)

#define OPH(RDS, STG, VM, qm, qn, bfq) do {                                  \
  RDS;                                                                       \
  __builtin_amdgcn_sched_barrier(0);                                         \
  STG;                                                                       \
  VM;                                                                        \
  __builtin_amdgcn_s_barrier();                                              \
  asm volatile("s_waitcnt lgkmcnt(0)" ::: "memory");                         \
  __builtin_amdgcn_sched_barrier(0);                                         \
  OMM(qm, qn, bfq);                                                          \
  __builtin_amdgcn_sched_barrier(0);                                         \
  __builtin_amdgcn_s_barrier();                                              \
} while (0)

#define OGEMM_BODY()                                                         \
  OSTG_A(0, 0, 0);                                                           \
  OSTG_B(0, 1, 0);                                                           \
  OSTG_B(0, 0, 0);                                                           \
  OSTG_A(0, 1, 0);                                                           \
  OSTG_A(1, 0, 64);                                                          \
  OSTG_B(1, 1, 64);                                                          \
  asm volatile("s_waitcnt vmcnt(5)" ::: "memory");                           \
  __syncthreads();                                                           \
  _Pragma("unroll 2")                                                        \
  for (int u = 0; u < 16; ++u) {                                             \
    int cur = u & 1, nxt = cur ^ 1;                                          \
    int k1 = (u >= 15 ? 15 : u + 1) * 64;                                    \
    int k2 = (u >= 14 ? 15 : u + 2) * 64;                                    \
    OPH({ ORD_A(0); ORD_B(0, bfA); }, OSTG_B(nxt, 0, k1),                    \
        asm volatile("s_waitcnt vmcnt(4)" ::: "memory"), 0, 0, bfA);         \
    OPH({ ORD_B(1, bfB); },           OSTG_A(nxt, 1, k1), (void)0, 0, 1, bfB); \
    OPH({ ORD_A(1); },                OSTG_A(cur, 0, k2), (void)0, 1, 1, bfB); \
    OPH({ (void)0; },                 OSTG_B(cur, 1, k2),                    \
        asm volatile("s_waitcnt vmcnt(5)" ::: "memory"), 1, 0, bfA);         \
  }

// ---------------- merged QKV GEMM: 512 blocks (256x128 tiles) --------------
// panel p (256 rows of merged 16384-row space): p<32 Q, 32..47 K, 48..63 V^T.
// Q output pre-scaled by s2=(1/8)*log2e (softmax works in scaled domain).
__global__ __launch_bounds__(512, 2) void k_gemm_qkv(const u16* __restrict__ xb,
                                                     const u16* __restrict__ cb,
                                                     const u16* __restrict__ wt,
                                                     u16* __restrict__ Qb,
                                                     u16* __restrict__ Kb,
                                                     u16* __restrict__ Vtb) {
  __shared__ u16 As8[2][16384];   // 256 x 64 per buf (64 KB)
  __shared__ u16 Bs8[2][8192];    // 128 x 64 per buf (32 KB)
  int lin = blockIdx.x;                     // 512 blocks
  int swz = (lin & 7) * 64 + (lin >> 3);    // bijective XCD chunking
  int p = swz >> 3, bx = swz & 7;
  const u16* A; const u16* Bt; u16* obf; int row0, mode;
  float osc;
  if (p < 32)      { A = xb; Bt = wt;           obf = Qb;  row0 = p * 256;        mode = 0; osc = 0.18033688011112042f; }
  else if (p < 48) { A = cb; Bt = wt + 1048576; obf = Kb;  row0 = (p - 32) * 256; mode = 0; osc = 1.0f; }
  else             { A = cb; Bt = wt + 2097152; obf = Vtb; row0 = (p - 48) * 256; mode = 1; osc = 1.0f; }
  int col0 = bx * 128;
  int t = threadIdx.x;
  int w = t >> 6, lane = t & 63, lrow = lane & 15, lgrp = lane >> 4;
  int wmo = (w >> 1) * 32, wno = (w & 1) * 32;   // 4M x 2N within quadrant
  int fo0 = (lgrp ^ (lrow & 7)) * 8;
  f32x4 acc[2][2][2][2] = {};
  bf16x8 af[2][2], bfA[2][2], bfB[2][2];
  int srow = t >> 3, sunit = (t & 7) ^ ((t >> 3) & 7);
  const u16* gA = A  + (size_t)(row0 + srow) * DM + sunit * 8;
  const u16* gB = Bt + (size_t)(col0 + srow) * DM + sunit * 8;

  OGEMM_BODY();

  #pragma unroll
  for (int qm = 0; qm < 2; ++qm)
    #pragma unroll
    for (int qn = 0; qn < 2; ++qn)
      #pragma unroll
      for (int mi = 0; mi < 2; ++mi)
        #pragma unroll
        for (int ni = 0; ni < 2; ++ni)
          #pragma unroll
          for (int j = 0; j < 4; ++j) {
            int gr = row0 + qm * 128 + wmo + mi * 16 + lgrp * 4 + j;
            int gc = col0 + qn * 64 + wno + ni * 16 + lrow;
            float v = acc[qm][qn][mi][ni][j] * osc;
            if (mode == 0) {
              obf[(size_t)gr * DM + gc] = f2bf(v);
            } else {
              int b = gr >> 10, m = gr & 1023;
              obf[((size_t)(b * DM + gc)) * MK + m] = f2bf(v);
            }
          }
}

// ---------------- out GEMM: 8-phase 256x128 (BK=64), 256 blocks ------------
__global__ __launch_bounds__(512, 2) void k_gemm_o(const u16* __restrict__ A,
                                                   const u16* __restrict__ Bt,
                                                   float* __restrict__ of32,
                                                   const float* __restrict__ bias) {
  __shared__ u16 As8[2][16384];   // 256 x 64 per buf (64 KB)
  __shared__ u16 Bs8[2][8192];    // 128 x 64 per buf (32 KB)
  int lin = blockIdx.x;                     // 256 blocks
  int swz = (lin & 7) * 32 + (lin >> 3);
  int p = swz >> 3, bx = swz & 7;
  int row0 = p * 256, col0 = bx * 128;
  int t = threadIdx.x;
  int w = t >> 6, lane = t & 63, lrow = lane & 15, lgrp = lane >> 4;
  int wmo = (w >> 1) * 32, wno = (w & 1) * 32;   // 4M x 2N within quadrant
  int fo0 = (lgrp ^ (lrow & 7)) * 8;
  f32x4 acc[2][2][2][2] = {};
  bf16x8 af[2][2], bfA[2][2], bfB[2][2];
  int srow = t >> 3, sunit = (t & 7) ^ ((t >> 3) & 7);
  const u16* gA = A  + (size_t)(row0 + srow) * DM + sunit * 8;
  const u16* gB = Bt + (size_t)(col0 + srow) * DM + sunit * 8;

  OGEMM_BODY();

  #pragma unroll
  for (int qm = 0; qm < 2; ++qm)
    #pragma unroll
    for (int qn = 0; qn < 2; ++qn)
      #pragma unroll
      for (int mi = 0; mi < 2; ++mi)
        #pragma unroll
        for (int ni = 0; ni < 2; ++ni)
          #pragma unroll
          for (int j = 0; j < 4; ++j) {
            int gr = row0 + qm * 128 + wmo + mi * 16 + lgrp * 4 + j;
            int gc = col0 + qn * 64 + wno + ni * 16 + lrow;
            of32[(size_t)gr * DM + gc] = acc[qm][qn][mi][ni][j] + bias[gc];
          }
}

// ---------------- flash attention (8-warp, QBLK=256, KVBLK=128) ------------
// 1-D grid 512 blocks, 512 threads. XCD-affinity swizzle (L2-resident K/V).
// KVBLK=128: one staged tile = 128 K-rows + 128 V-cols, processed as two
// 64-row subtiles per barrier; defer-max softmax per subtile (known-good
// numerics); L via MFMA ones-trick; packed-f32 bias/rescale; raw v_exp_f32.
#define BUILD_PFRAG(sv, base, frag) {                     \
  unsigned a_ = cvtpk(sv[base + 0], sv[base + 1]);        \
  unsigned c_ = cvtpk(sv[base + 2], sv[base + 3]);        \
  unsigned b_ = cvtpk(sv[base + 4], sv[base + 5]);        \
  unsigned d_ = cvtpk(sv[base + 6], sv[base + 7]);        \
  asm("v_permlane32_swap_b32 %0, %1" : "+v"(a_), "+v"(b_)); \
  asm("v_permlane32_swap_b32 %0, %1" : "+v"(c_), "+v"(d_)); \
  union { unsigned w[4]; bf16x8 v; } u_;                  \
  u_.w[0] = a_;  u_.w[1] = c_;                            \
  u_.w[2] = b_;  u_.w[3] = d_;                            \
  frag = u_.v; }

#define PV_CHUNK(sv, base, c, ms) {                                           \
  bf16x8 pf_; BUILD_PFRAG(sv, base, pf_);                                     \
  int mo_ = (ms) * 64 + ((((c) * 16 + hi * 8)) ^ sw);                         \
  bf16x8 vf0_ = *(const bf16x8*)&Vl[cur][ln * 128 + mo_];                     \
  bf16x8 vf1_ = *(const bf16x8*)&Vl[cur][(32 + ln) * 128 + mo_];              \
  __builtin_amdgcn_s_setprio(1);                                              \
  o0 = __builtin_amdgcn_mfma_f32_32x32x16_bf16(vf0_, pf_, o0, 0, 0, 0);       \
  o1 = __builtin_amdgcn_mfma_f32_32x32x16_bf16(vf1_, pf_, o1, 0, 0, 0);       \
  Lacc = __builtin_amdgcn_mfma_f32_32x32x16_bf16(onesf, pf_, Lacc, 0, 0, 0);  \
  __builtin_amdgcn_s_setprio(0); }

// depth-3 max of 16 via v_max3
__device__ __forceinline__ float max16(const f32x16 &v) {
  float m0 = max3f(v[0], v[1], v[2]);
  float m1 = max3f(v[3], v[4], v[5]);
  float m2 = max3f(v[6], v[7], v[8]);
  float m3 = max3f(v[9], v[10], v[11]);
  float m4 = max3f(v[12], v[13], v[14]);
  float a = max3f(m0, m1, m2);
  float b = max3f(m3, m4, v[15]);
  return fmaxf(a, b);
}

__global__ __launch_bounds__(512) void k_attn(const u16* __restrict__ Q,
                                              const u16* __restrict__ K,
                                              const u16* __restrict__ Vt,
                                              u16* __restrict__ O) {
  __shared__ __align__(16) u16 Kl[2][8192];   // [m=128][d=64], elem ^ ((m&7)<<3)
  __shared__ __align__(16) u16 Vl[2][8192];   // [d=64][m=128], elem ^ ((d&7)<<3)
  // XCD-affinity: xcd = wgid&7 owns bh range [xcd*8, xcd*8+8)
  int wgid = blockIdx.x;
  int bh = (wgid & 7) * 8 + (wgid >> 6);
  int nt = (wgid >> 3) & 7;
  int b = bh >> 4, h = bh & 15;
  int n0 = nt * 256;
  int t = threadIdx.x, w = t >> 6, lane = t & 63;
  int ln = lane & 31, hi = lane >> 5;

  int qrow = n0 + w * 32 + ln;
  const u16* qp = &Q[(((size_t)(b * NQ + qrow)) * HEADS + h) * DHEAD + hi * 8];
  bf16x8 qf0 = *(const bf16x8*)(qp);
  bf16x8 qf1 = *(const bf16x8*)(qp + 16);
  bf16x8 qf2 = *(const bf16x8*)(qp + 32);
  bf16x8 qf3 = *(const bf16x8*)(qp + 48);

  // all-ones A fragment for the L-sum MFMA (bf16 1.0 = 0x3F80)
  const short one_ = (short)0x3F80;
  bf16x8 onesf = {one_, one_, one_, one_, one_, one_, one_, one_};

  f32x16 o0 = {}, o1 = {}, Lacc = {};
  float M_ = -1e30f;

  // staging: K rows srK & srK+64 (8 units each); V d-rows srV & srV+32 (16 units)
  int srK = t >> 3, uK = t & 7;
  const u16* kg = &K[(((size_t)(b * MK + srK)) * HEADS + h) * DHEAD + uK * 8];
  int sdK = srK * 64 + ((uK * 8) ^ ((srK & 7) << 3));
  int srV = t >> 4, uV = t & 15;
  const u16* vg = &Vt[((size_t)(b * DM) + h * DHEAD + srV) * MK + uV * 8];
  int sdV = srV * 128 + ((uV * 8) ^ ((srV & 7) << 3));
  int sw = (ln & 7) << 3;

  // tile 0 stage + single barrier
  int4 kv0 = *(const int4*)kg;
  int4 kv1 = *(const int4*)(kg + 65536);     // +64 K-rows
  int4 vv0 = *(const int4*)vg;
  int4 vv1 = *(const int4*)(vg + 32 * MK);   // +32 d-rows
  *(int4*)&Kl[0][sdK] = kv0;  *(int4*)&Kl[0][sdK + 4096] = kv1;
  *(int4*)&Vl[0][sdV] = vv0;  *(int4*)&Vl[0][sdV + 4096] = vv1;
  __syncthreads();

  for (int it = 0; it < 8; ++it) {
    int cur = it & 1;
    if (it < 7) {   // issue next-tile global loads; land after compute
      const u16* kn = kg + (size_t)(it + 1) * 131072;   // 128 rows * 1024
      const u16* vn = vg + (it + 1) * 128;
      kv0 = *(const int4*)kn;  kv1 = *(const int4*)(kn + 65536);
      vv0 = *(const int4*)vn;  vv1 = *(const int4*)(vn + 32 * MK);
    }

    #pragma unroll
    for (int ms = 0; ms < 2; ++ms) {
      // S'^T = K . Q^T (pre-scaled): lane holds S'[m = ms*64 + ...][q=ln]
      f32x16 s0 = {}, s1 = {};
      __builtin_amdgcn_s_setprio(1);
      #pragma unroll
      for (int kd = 0; kd < 4; ++kd) {
        int doff = (kd * 16 + hi * 8) ^ sw;
        bf16x8 kf0 = *(const bf16x8*)&Kl[cur][(ms * 64 + ln) * 64 + doff];
        bf16x8 kf1 = *(const bf16x8*)&Kl[cur][(ms * 64 + 32 + ln) * 64 + doff];
        bf16x8 qk = kd == 0 ? qf0 : kd == 1 ? qf1 : kd == 2 ? qf2 : qf3;
        s0 = __builtin_amdgcn_mfma_f32_32x32x16_bf16(kf0, qk, s0, 0, 0, 0);
        s1 = __builtin_amdgcn_mfma_f32_32x32x16_bf16(kf1, qk, s1, 0, 0, 0);
      }
      __builtin_amdgcn_s_setprio(0);

      float vm = fmaxf(max16(s0), max16(s1));

      // defer-max (T13), scaled domain: THR = 8*s2 = 1.4427
      if (!__all(vm - M_ <= 1.44269504f)) {
        float vm2 = fmaxf(vm, __shfl_xor(vm, 32));
        float mn = fmaxf(M_, vm2);
        float rc = fexp2(M_ - mn);
        M_ = mn;
        Lacc[0] *= rc;
        f32x2 rc2 = {rc, rc};
        f32x2* o0p = (f32x2*)&o0;
        f32x2* o1p = (f32x2*)&o1;
        #pragma unroll
        for (int i = 0; i < 8; ++i) { o0p[i] = pk_mul(o0p[i], rc2); }
        #pragma unroll
        for (int i = 0; i < 8; ++i) { o1p[i] = pk_mul(o1p[i], rc2); }
      }
      // P = exp2(S' - M_): packed bias-add then raw v_exp
      f32x2 nb2 = {-M_, -M_};
      f32x2* s0p = (f32x2*)&s0;
      f32x2* s1p = (f32x2*)&s1;
      #pragma unroll
      for (int i = 0; i < 8; ++i) s0p[i] = pk_add(s0p[i], nb2);
      #pragma unroll
      for (int i = 0; i < 8; ++i) s1p[i] = pk_add(s1p[i], nb2);
      #pragma unroll
      for (int i = 0; i < 16; ++i) s0[i] = fexp2(s0[i]);
      #pragma unroll
      for (int i = 0; i < 16; ++i) s1[i] = fexp2(s1[i]);

      // O^T += V^T . P^T ; Lacc += ones . P^T (collective row-sum)
      PV_CHUNK(s0, 0, 0, ms);
      PV_CHUNK(s0, 8, 1, ms);
      PV_CHUNK(s1, 0, 2, ms);
      PV_CHUNK(s1, 8, 3, ms);
    }

    if (it < 7) {   // write next tile into the other buffer, then ONE barrier
      *(int4*)&Kl[cur ^ 1][sdK] = kv0;  *(int4*)&Kl[cur ^ 1][sdK + 4096] = kv1;
      *(int4*)&Vl[cur ^ 1][sdV] = vv0;  *(int4*)&Vl[cur ^ 1][sdV + 4096] = vv1;
    }
    __syncthreads();
  }

  float inv = 1.0f / Lacc[0];   // complete sum (MFMA is lane-collective)
  u16* ob = (u16*)&O[(((size_t)(b * NQ + qrow)) * HEADS + h) * DHEAD];
  #pragma unroll
  for (int g = 0; g < 4; ++g) {
    union { u16 h4[4]; uint2 v; } r0, r1;
    #pragma unroll
    for (int s = 0; s < 4; ++s) {
      r0.h4[s] = f2bf(o0[4 * g + s] * inv);
      r1.h4[s] = f2bf(o1[4 * g + s] * inv);
    }
    *(uint2*)(ob + 8 * g + 4 * hi) = r0.v;
    *(uint2*)(ob + 32 + 8 * g + 4 * hi) = r1.v;
  }
}

// ---------------------------------------------------------------------------
extern "C" void kernel_launch(void* const* d_in, const int* in_sizes, int n_in,
                              void* d_out, int out_size, void* d_ws, size_t ws_size,
                              hipStream_t stream) {
  (void)in_sizes; (void)n_in; (void)out_size; (void)ws_size;
  const float* x   = (const float*)d_in[0];
  const float* ctx = (const float*)d_in[1];
  const float* Wq  = (const float*)d_in[2];
  const float* Wk  = (const float*)d_in[3];
  const float* Wv  = (const float*)d_in[4];
  const float* Wo  = (const float*)d_in[5];
  const float* bo  = (const float*)d_in[6];
  float* out = (float*)d_out;
  char* ws = (char*)d_ws;
  const size_t MB = 1u << 20;
  u16* xb  = (u16*)(ws);             // 16 MB: x bf16 [8192][1024]
  u16* cb  = (u16*)(ws + 16 * MB);   //  8 MB: ctx bf16 [4096][1024]
  u16* wt  = (u16*)(ws + 24 * MB);   //  8 MB: WqT,WkT,WvT,WoT bf16 [1024][1024] each
  u16* Qb  = (u16*)(ws + 32 * MB);   // 16 MB: Q bf16 [b,n,h,d] (pre-scaled by s2)
  u16* Kb  = (u16*)(ws + 48 * MB);   //  8 MB: K bf16 [b,m,h,d]
  u16* Vtb = (u16*)(ws + 56 * MB);   //  8 MB: Vt bf16 [b,h,d,m]
  u16* Ab  = (u16*)(ws + 64 * MB);   // 16 MB: attn out bf16 [b,n,h*64+d]

  k_pre<<<10240, 256, 0, stream>>>(x, ctx, Wq, Wk, Wv, Wo, xb, cb, wt);

  k_gemm_qkv<<<512, 512, 0, stream>>>(xb, cb, wt, Qb, Kb, Vtb);

  k_attn<<<512, 512, 0, stream>>>(Qb, Kb, Vtb, Ab);

  k_gemm_o<<<256, 512, 0, stream>>>(Ab, wt + 3145728, out, bo);
}

// Round 14
// 151.495 us; speedup vs baseline: 1.0641x; 1.0641x over previous
//
#include <hip/hip_runtime.h>
#include <math.h>

// CrossAttention: B=4, N=2048, M=1024, HEADS=16, DHEAD=64, model dim 1024.
// fused preprocessing (x-cvt + ctx-cvt + weight transpose in ONE launch);
// merged QKV GEMM on the 8-phase 256x256 template (R7 pinned variant);
// out GEMM on the 8-phase 256x128 variant; flash attention (8-warp QBLK=256,
// KVBLK=128, R7 defer-max softmax per 64-row subtile, dbuf K/V, XCD-affinity
// swizzle, L-sum via MFMA ones-trick, raw v_exp_f32, permlane32_swap pack).
// [R14 = revert to R12, the measured best at 152.2 us.]

#define HEADS 16
#define DHEAD 64
#define DM    1024
#define BQ    4
#define NQ    2048
#define MK    1024

typedef unsigned short u16;
typedef __attribute__((ext_vector_type(8))) short bf16x8;
typedef __attribute__((ext_vector_type(2))) float f32x2;
typedef __attribute__((ext_vector_type(4))) float f32x4;
typedef __attribute__((ext_vector_type(16))) float f32x16;

__device__ __forceinline__ u16 f2bf(float f) {
  unsigned u = __builtin_bit_cast(unsigned, f);
  u = u + 0x7FFFu + ((u >> 16) & 1u);   // round-to-nearest-even
  return (u16)(u >> 16);
}

// packed bf16 word via HW cvt: low half <- %1, high half <- %2
__device__ __forceinline__ unsigned cvtpk(float lo, float hi2) {
  unsigned r;
  asm("v_cvt_pk_bf16_f32 %0, %1, %2" : "=v"(r) : "v"(lo), "v"(hi2));
  return r;
}

__device__ __forceinline__ float max3f(float a, float b, float c) {
  float d;
  asm("v_max3_f32 %0, %1, %2, %3" : "=v"(d) : "v"(a), "v"(b), "v"(c));
  return d;
}

// raw HW exp2 (skips libm fixup path)
__device__ __forceinline__ float fexp2(float x) {
  float r;
  asm("v_exp_f32 %0, %1" : "=v"(r) : "v"(x));
  return r;
}

// packed f32 ops (VOP3P, full-rate on CDNA2+)
__device__ __forceinline__ f32x2 pk_add(f32x2 a, f32x2 b) {
  f32x2 d;
  asm("v_pk_add_f32 %0, %1, %2" : "=v"(d) : "v"(a), "v"(b));
  return d;
}
__device__ __forceinline__ f32x2 pk_mul(f32x2 a, f32x2 b) {
  f32x2 d;
  asm("v_pk_mul_f32 %0, %1, %2" : "=v"(d) : "v"(a), "v"(b));
  return d;
}

// async global->LDS, 16B per lane; LDS dst = wave-uniform base + lane*16
__device__ __forceinline__ void gld16(const u16* g, u16* l) {
  __builtin_amdgcn_global_load_lds((const __attribute__((address_space(1))) void*)g,
                                   (__attribute__((address_space(3))) void*)l,
                                   16, 0, 0);
}

// ---------------- fused preprocessing: cvt(x) + cvt(ctx) + transpose(W) ----
// grid 10240 x 256 threads:
//   [0,4096)      x fp32 -> bf16, 8 elems/thread (n8 = 1048576)
//   [4096,6144)   ctx fp32 -> bf16 (n8 = 524288)
//   [6144,10240)  W[k][n] -> Wt[n][k] bf16, 32x32 tiles, 4 weights
__global__ void k_pre(const float* __restrict__ x, const float* __restrict__ ctx,
                      const float* __restrict__ W0, const float* __restrict__ W1,
                      const float* __restrict__ W2, const float* __restrict__ W3,
                      u16* __restrict__ xb, u16* __restrict__ cb,
                      u16* __restrict__ wt) {
  __shared__ float tsh[32][33];
  int blk = blockIdx.x, t = threadIdx.x;
  if (blk < 6144) {
    const float* in; u16* out; int i;
    if (blk < 4096) { in = x;   out = xb; i = blk * 256 + t; }
    else            { in = ctx; out = cb; i = (blk - 4096) * 256 + t; }
    float4 a = ((const float4*)in)[i * 2];
    float4 b = ((const float4*)in)[i * 2 + 1];
    union { u16 h[8]; int4 v; } r;
    r.h[0] = f2bf(a.x); r.h[1] = f2bf(a.y); r.h[2] = f2bf(a.z); r.h[3] = f2bf(a.w);
    r.h[4] = f2bf(b.x); r.h[5] = f2bf(b.y); r.h[6] = f2bf(b.z); r.h[7] = f2bf(b.w);
    ((int4*)out)[i] = r.v;
    return;
  }
  int vb = blk - 6144;                 // 4096 transpose tiles
  int z = vb >> 10, rem = vb & 1023;
  int by = rem >> 5, bx = rem & 31;
  const float* W = z == 0 ? W0 : z == 1 ? W1 : z == 2 ? W2 : W3;
  u16* o = wt + (size_t)z * DM * DM;
  int r0 = by * 32, c0 = bx * 32;
  int tx = t & 31, ty = t >> 5;
  for (int i = ty; i < 32; i += 8) tsh[i][tx] = W[(size_t)(r0 + i) * DM + c0 + tx];
  __syncthreads();
  for (int i = ty; i < 32; i += 8) o[(size_t)(c0 + i) * DM + r0 + tx] = f2bf(tsh[tx][i]);
}

// ============ 8-phase 256x256 GEMM core (BK=64, quadrant-per-phase) ========
// R7 pinned variant (best measured: 62.4 us QKV).
#define VM6 asm volatile("s_waitcnt vmcnt(6)" ::: "memory")

#define STAGE_A8(bufi, h, kof) do {                                          \
  gld16(gA + (size_t)(h) * 131072 + (kof), &As8[bufi][(h) * 8192 + w * 512]); \
  gld16(gA + (size_t)(h) * 131072 + 65536 + (kof),                           \
        &As8[bufi][(h) * 8192 + 4096 + w * 512]);                            \
} while (0)

#define STAGE_B8(bufi, h, kof) do {                                          \
  gld16(gB + (size_t)(h) * 131072 + (kof), &Bs8[bufi][(h) * 8192 + w * 512]); \
  gld16(gB + (size_t)(h) * 131072 + 65536 + (kof),                           \
        &Bs8[bufi][(h) * 8192 + 4096 + w * 512]);                            \
} while (0)

#define RD_A8(qm) do { _Pragma("unroll")                                     \
  for (int mi = 0; mi < 4; ++mi) {                                           \
    const u16* pa = &As8[cur][((qm) * 128 + wmo + mi * 16 + lrow) * 64];     \
    af8[mi][0] = *(const bf16x8*)(pa + fo0);                                 \
    af8[mi][1] = *(const bf16x8*)(pa + (fo0 ^ 32));                          \
  } } while (0)

#define RD_B8(qn) do { _Pragma("unroll")                                     \
  for (int ni = 0; ni < 2; ++ni) {                                           \
    const u16* pb = &Bs8[cur][((qn) * 128 + wno + ni * 16 + lrow) * 64];     \
    bf8[ni][0] = *(const bf16x8*)(pb + fo0);                                 \
    bf8[ni][1] = *(const bf16x8*)(pb + (fo0 ^ 32));                          \
  } } while (0)

#define MM16(qm, qn) do {                                                    \
  __builtin_amdgcn_s_setprio(1);                                             \
  _Pragma("unroll")                                                          \
  for (int mi = 0; mi < 4; ++mi)                                             \
    _Pragma("unroll")                                                        \
    for (int ni = 0; ni < 2; ++ni) {                                         \
      acc[qm][qn][mi][ni] = __builtin_amdgcn_mfma_f32_16x16x32_bf16(         \
          af8[mi][0], bf8[ni][0], acc[qm][qn][mi][ni], 0, 0, 0);             \
      acc[qm][qn][mi][ni] = __builtin_amdgcn_mfma_f32_16x16x32_bf16(         \
          af8[mi][1], bf8[ni][1], acc[qm][qn][mi][ni], 0, 0, 0);             \
    }                                                                        \
  __builtin_amdgcn_s_setprio(0);                                             \
} while (0)

#define PH8(RDS, STG, VM, qm, qn) do {                                       \
  RDS;                                                                       \
  __builtin_amdgcn_sched_barrier(0);                                         \
  STG;                                                                       \
  VM;                                                                        \
  __builtin_amdgcn_s_barrier();                                              \
  asm volatile("s_waitcnt lgkmcnt(0)" ::: "memory");                         \
  __builtin_amdgcn_sched_barrier(0);                                         \
  MM16(qm, qn);                                                              \
  __builtin_amdgcn_sched_barrier(0);                                         \
  __builtin_amdgcn_s_barrier();                                              \
} while (0)

// ---------------- merged QKV GEMM: 256 blocks (1/CU), XCD-chunked ----------
// panel p (256 rows of merged 16384-row space): p<32 Q, 32..47 K, 48..63 V^T.
// Q output pre-scaled by s2=(1/8)*log2e (softmax works in scaled domain).
__global__ __launch_bounds__(512, 2) void k_gemm_qkv(const u16* __restrict__ xb,
                                                     const u16* __restrict__ cb,
                                                     const u16* __restrict__ wt,
                                                     u16* __restrict__ Qb,
                                                     u16* __restrict__ Kb,
                                                     u16* __restrict__ Vtb) {
  __shared__ u16 As8[2][16384];   // 256 x 64 per buf
  __shared__ u16 Bs8[2][16384];
  int lin = blockIdx.x;
  int swz = (lin & 7) * 32 + (lin >> 3);   // 256 wgs, bijective XCD chunking
  int p = swz >> 2, bx = swz & 3;
  const u16* A; const u16* Bt; u16* obf; int row0, mode;
  float osc;
  if (p < 32)      { A = xb; Bt = wt;           obf = Qb;  row0 = p * 256;        mode = 0; osc = 0.18033688011112042f; }
  else if (p < 48) { A = cb; Bt = wt + 1048576; obf = Kb;  row0 = (p - 32) * 256; mode = 0; osc = 1.0f; }
  else             { A = cb; Bt = wt + 2097152; obf = Vtb; row0 = (p - 48) * 256; mode = 1; osc = 1.0f; }
  int col0 = bx * 256;
  int t = threadIdx.x;
  int w = t >> 6, lane = t & 63, lrow = lane & 15, lgrp = lane >> 4;
  int wmo = (w >> 2) * 64, wno = (w & 3) * 32;
  int fo0 = (lgrp ^ (lrow & 7)) * 8;        // swizzled 16B-unit for frag reads
  f32x4 acc[2][2][4][2] = {};
  bf16x8 af8[4][2], bf8[2][2];
  // pre-swizzled global source: thread t covers row (t>>3), 16B-unit (t&7)
  int srow = t >> 3, sunit = (t & 7) ^ ((t >> 3) & 7);
  const u16* gA = A  + (size_t)(row0 + srow) * DM + sunit * 8;
  const u16* gB = Bt + (size_t)(col0 + srow) * DM + sunit * 8;

  // prologue: A0(0), B1(0), B0(0), A1(0), A0(1), B1(1)  (12 loads)
  STAGE_A8(0, 0, 0);
  STAGE_B8(0, 1, 0);
  STAGE_B8(0, 0, 0);
  STAGE_A8(0, 1, 0);
  STAGE_A8(1, 0, 64);
  STAGE_B8(1, 1, 64);
  VM6;                      // forces A0(0), B1(0), B0(0)
  __syncthreads();

  #pragma unroll 2
  for (int u = 0; u < 16; ++u) {
    int cur = u & 1, nxt = cur ^ 1;
    int k1 = (u >= 15 ? 15 : u + 1) * 64;   // tail: clamped re-stage (unused)
    int k2 = (u >= 14 ? 15 : u + 2) * 64;
    PH8({ RD_A8(0); RD_B8(0); }, STAGE_B8(nxt, 0, k1), VM6,     0, 0);
    PH8({ RD_B8(1); },           STAGE_A8(nxt, 1, k1), (void)0, 0, 1);
    PH8({ RD_A8(1); },           STAGE_A8(cur, 0, k2), (void)0, 1, 1);
    PH8({ RD_B8(0); },           STAGE_B8(cur, 1, k2), VM6,     1, 0);
  }

  #pragma unroll
  for (int qm = 0; qm < 2; ++qm)
    #pragma unroll
    for (int qn = 0; qn < 2; ++qn)
      #pragma unroll
      for (int mi = 0; mi < 4; ++mi)
        #pragma unroll
        for (int ni = 0; ni < 2; ++ni)
          #pragma unroll
          for (int j = 0; j < 4; ++j) {
            int gr = row0 + qm * 128 + wmo + mi * 16 + lgrp * 4 + j;
            int gc = col0 + qn * 128 + wno + ni * 16 + lrow;
            float v = acc[qm][qn][mi][ni][j] * osc;
            if (mode == 0) {
              obf[(size_t)gr * DM + gc] = f2bf(v);
            } else {
              int b = gr >> 10, m = gr & 1023;
              obf[((size_t)(b * DM + gc)) * MK + m] = f2bf(v);
            }
          }
}

// ---------------- out GEMM: 8-phase 256x128 (BK=64), 256 blocks ------------
#define OSTG_A(bufi, h, kof) do {                                            \
  gld16(gA + (size_t)(h) * 131072 + (kof), &As8[bufi][(h) * 8192 + w * 512]); \
  gld16(gA + (size_t)(h) * 131072 + 65536 + (kof),                           \
        &As8[bufi][(h) * 8192 + 4096 + w * 512]);                            \
} while (0)

#define OSTG_B(bufi, h, kof)                                                 \
  gld16(gB + (size_t)(h) * 65536 + (kof), &Bs8[bufi][(h) * 4096 + w * 512])

#define ORD_A(qm) do { _Pragma("unroll")                                     \
  for (int mi = 0; mi < 2; ++mi) {                                           \
    const u16* pa = &As8[cur][((qm) * 128 + wmo + mi * 16 + lrow) * 64];     \
    af[mi][0] = *(const bf16x8*)(pa + fo0);                                  \
    af[mi][1] = *(const bf16x8*)(pa + (fo0 ^ 32));                           \
  } } while (0)

#define ORD_B(qn, dst) do { _Pragma("unroll")                                \
  for (int ni = 0; ni < 2; ++ni) {                                           \
    const u16* pb = &Bs8[cur][((qn) * 64 + wno + ni * 16 + lrow) * 64];      \
    dst[ni][0] = *(const bf16x8*)(pb + fo0);                                 \
    dst[ni][1] = *(const bf16x8*)(pb + (fo0 ^ 32));                          \
  } } while (0)

#define OMM(qm, qn, bfq) do {                                                \
  __builtin_amdgcn_s_setprio(1);                                             \
  _Pragma("unroll")                                                          \
  for (int mi = 0; mi < 2; ++mi)                                             \
    _Pragma("unroll")                                                        \
    for (int ni = 0; ni < 2; ++ni) {                                         \
      acc[qm][qn][mi][ni] = __builtin_amdgcn_mfma_f32_16x16x32_bf16(         \
          af[mi][0], bfq[ni][0], acc[qm][qn][mi][ni], 0, 0, 0);              \
      acc[qm][qn][mi][ni] = __builtin_amdgcn_mfma_f32_16x16x32_bf16(         \
          af[mi][1], bfq[ni][1], acc[qm][qn][mi][ni], 0, 0, 0);              \
    }                                                                        \
  __builtin_amdgcn_s_setprio(0);                                             \
} while (0)

#define OPH(RDS, STG, VM, qm, qn, bfq) do {                                  \
  RDS;                                                                       \
  __builtin_amdgcn_sched_barrier(0);                                         \
  STG;                                                                       \
  VM;                                                                        \
  __builtin_amdgcn_s_barrier();                                              \
  asm volatile("s_waitcnt lgkmcnt(0)" ::: "memory");                         \
  __builtin_amdgcn_sched_barrier(0);                                         \
  OMM(qm, qn, bfq);                                                          \
  __builtin_amdgcn_sched_barrier(0);                                         \
  __builtin_amdgcn_s_barrier();                                              \
} while (0)

__global__ __launch_bounds__(512, 2) void k_gemm_o(const u16* __restrict__ A,
                                                   const u16* __restrict__ Bt,
                                                   float* __restrict__ of32,
                                                   const float* __restrict__ bias) {
  __shared__ u16 As8[2][16384];   // 256 x 64 per buf (64 KB)
  __shared__ u16 Bs8[2][8192];    // 128 x 64 per buf (32 KB)
  int lin = blockIdx.x;                     // 256 blocks
  int swz = (lin & 7) * 32 + (lin >> 3);
  int p = swz >> 3, bx = swz & 7;
  int row0 = p * 256, col0 = bx * 128;
  int t = threadIdx.x;
  int w = t >> 6, lane = t & 63, lrow = lane & 15, lgrp = lane >> 4;
  int wmo = (w >> 1) * 32, wno = (w & 1) * 32;   // 4M x 2N within quadrant
  int fo0 = (lgrp ^ (lrow & 7)) * 8;
  f32x4 acc[2][2][2][2] = {};
  bf16x8 af[2][2], bfA[2][2], bfB[2][2];
  int srow = t >> 3, sunit = (t & 7) ^ ((t >> 3) & 7);
  const u16* gA = A  + (size_t)(row0 + srow) * DM + sunit * 8;
  const u16* gB = Bt + (size_t)(col0 + srow) * DM + sunit * 8;

  // prologue pushes: A0(0)[2], B1(0)[1], B0(0)[1], A1(0)[2], A0(1)[2], B1(1)[1]
  OSTG_A(0, 0, 0);
  OSTG_B(0, 1, 0);
  OSTG_B(0, 0, 0);
  OSTG_A(0, 1, 0);
  OSTG_A(1, 0, 64);
  OSTG_B(1, 1, 64);
  asm volatile("s_waitcnt vmcnt(5)" ::: "memory");   // forces A0(0),B1(0),B0(0)
  __syncthreads();

  #pragma unroll 2
  for (int u = 0; u < 16; ++u) {
    int cur = u & 1, nxt = cur ^ 1;
    int k1 = (u >= 15 ? 15 : u + 1) * 64;
    int k2 = (u >= 14 ? 15 : u + 2) * 64;
    OPH({ ORD_A(0); ORD_B(0, bfA); }, OSTG_B(nxt, 0, k1),
        asm volatile("s_waitcnt vmcnt(4)" ::: "memory"), 0, 0, bfA);
    OPH({ ORD_B(1, bfB); },           OSTG_A(nxt, 1, k1), (void)0, 0, 1, bfB);
    OPH({ ORD_A(1); },                OSTG_A(cur, 0, k2), (void)0, 1, 1, bfB);
    OPH({ (void)0; },                 OSTG_B(cur, 1, k2),
        asm volatile("s_waitcnt vmcnt(5)" ::: "memory"), 1, 0, bfA);
  }

  #pragma unroll
  for (int qm = 0; qm < 2; ++qm)
    #pragma unroll
    for (int qn = 0; qn < 2; ++qn)
      #pragma unroll
      for (int mi = 0; mi < 2; ++mi)
        #pragma unroll
        for (int ni = 0; ni < 2; ++ni)
          #pragma unroll
          for (int j = 0; j < 4; ++j) {
            int gr = row0 + qm * 128 + wmo + mi * 16 + lgrp * 4 + j;
            int gc = col0 + qn * 64 + wno + ni * 16 + lrow;
            of32[(size_t)gr * DM + gc] = acc[qm][qn][mi][ni][j] + bias[gc];
          }
}

// ---------------- flash attention (8-warp, QBLK=256, KVBLK=128) ------------
// 1-D grid 512 blocks, 512 threads. XCD-affinity swizzle (L2-resident K/V).
// KVBLK=128: one staged tile = 128 K-rows + 128 V-cols, processed as two
// 64-row subtiles per barrier; defer-max softmax per subtile (known-good
// numerics); L via MFMA ones-trick; packed-f32 bias/rescale; raw v_exp_f32.
#define BUILD_PFRAG(sv, base, frag) {                     \
  unsigned a_ = cvtpk(sv[base + 0], sv[base + 1]);        \
  unsigned c_ = cvtpk(sv[base + 2], sv[base + 3]);        \
  unsigned b_ = cvtpk(sv[base + 4], sv[base + 5]);        \
  unsigned d_ = cvtpk(sv[base + 6], sv[base + 7]);        \
  asm("v_permlane32_swap_b32 %0, %1" : "+v"(a_), "+v"(b_)); \
  asm("v_permlane32_swap_b32 %0, %1" : "+v"(c_), "+v"(d_)); \
  union { unsigned w[4]; bf16x8 v; } u_;                  \
  u_.w[0] = a_;  u_.w[1] = c_;                            \
  u_.w[2] = b_;  u_.w[3] = d_;                            \
  frag = u_.v; }

#define PV_CHUNK(sv, base, c, ms) {                                           \
  bf16x8 pf_; BUILD_PFRAG(sv, base, pf_);                                     \
  int mo_ = (ms) * 64 + ((((c) * 16 + hi * 8)) ^ sw);                         \
  bf16x8 vf0_ = *(const bf16x8*)&Vl[cur][ln * 128 + mo_];                     \
  bf16x8 vf1_ = *(const bf16x8*)&Vl[cur][(32 + ln) * 128 + mo_];              \
  __builtin_amdgcn_s_setprio(1);                                              \
  o0 = __builtin_amdgcn_mfma_f32_32x32x16_bf16(vf0_, pf_, o0, 0, 0, 0);       \
  o1 = __builtin_amdgcn_mfma_f32_32x32x16_bf16(vf1_, pf_, o1, 0, 0, 0);       \
  Lacc = __builtin_amdgcn_mfma_f32_32x32x16_bf16(onesf, pf_, Lacc, 0, 0, 0);  \
  __builtin_amdgcn_s_setprio(0); }

// depth-3 max of 16 via v_max3
__device__ __forceinline__ float max16(const f32x16 &v) {
  float m0 = max3f(v[0], v[1], v[2]);
  float m1 = max3f(v[3], v[4], v[5]);
  float m2 = max3f(v[6], v[7], v[8]);
  float m3 = max3f(v[9], v[10], v[11]);
  float m4 = max3f(v[12], v[13], v[14]);
  float a = max3f(m0, m1, m2);
  float b = max3f(m3, m4, v[15]);
  return fmaxf(a, b);
}

__global__ __launch_bounds__(512) void k_attn(const u16* __restrict__ Q,
                                              const u16* __restrict__ K,
                                              const u16* __restrict__ Vt,
                                              u16* __restrict__ O) {
  __shared__ __align__(16) u16 Kl[2][8192];   // [m=128][d=64], elem ^ ((m&7)<<3)
  __shared__ __align__(16) u16 Vl[2][8192];   // [d=64][m=128], elem ^ ((d&7)<<3)
  // XCD-affinity: xcd = wgid&7 owns bh range [xcd*8, xcd*8+8)
  int wgid = blockIdx.x;
  int bh = (wgid & 7) * 8 + (wgid >> 6);
  int nt = (wgid >> 3) & 7;
  int b = bh >> 4, h = bh & 15;
  int n0 = nt * 256;
  int t = threadIdx.x, w = t >> 6, lane = t & 63;
  int ln = lane & 31, hi = lane >> 5;

  int qrow = n0 + w * 32 + ln;
  const u16* qp = &Q[(((size_t)(b * NQ + qrow)) * HEADS + h) * DHEAD + hi * 8];
  bf16x8 qf0 = *(const bf16x8*)(qp);
  bf16x8 qf1 = *(const bf16x8*)(qp + 16);
  bf16x8 qf2 = *(const bf16x8*)(qp + 32);
  bf16x8 qf3 = *(const bf16x8*)(qp + 48);

  // all-ones A fragment for the L-sum MFMA (bf16 1.0 = 0x3F80)
  const short one_ = (short)0x3F80;
  bf16x8 onesf = {one_, one_, one_, one_, one_, one_, one_, one_};

  f32x16 o0 = {}, o1 = {}, Lacc = {};
  float M_ = -1e30f;

  // staging: K rows srK & srK+64 (8 units each); V d-rows srV & srV+32 (16 units)
  int srK = t >> 3, uK = t & 7;
  const u16* kg = &K[(((size_t)(b * MK + srK)) * HEADS + h) * DHEAD + uK * 8];
  int sdK = srK * 64 + ((uK * 8) ^ ((srK & 7) << 3));
  int srV = t >> 4, uV = t & 15;
  const u16* vg = &Vt[((size_t)(b * DM) + h * DHEAD + srV) * MK + uV * 8];
  int sdV = srV * 128 + ((uV * 8) ^ ((srV & 7) << 3));
  int sw = (ln & 7) << 3;

  // tile 0 stage + single barrier
  int4 kv0 = *(const int4*)kg;
  int4 kv1 = *(const int4*)(kg + 65536);     // +64 K-rows
  int4 vv0 = *(const int4*)vg;
  int4 vv1 = *(const int4*)(vg + 32 * MK);   // +32 d-rows
  *(int4*)&Kl[0][sdK] = kv0;  *(int4*)&Kl[0][sdK + 4096] = kv1;
  *(int4*)&Vl[0][sdV] = vv0;  *(int4*)&Vl[0][sdV + 4096] = vv1;
  __syncthreads();

  for (int it = 0; it < 8; ++it) {
    int cur = it & 1;
    if (it < 7) {   // issue next-tile global loads; land after compute
      const u16* kn = kg + (size_t)(it + 1) * 131072;   // 128 rows * 1024
      const u16* vn = vg + (it + 1) * 128;
      kv0 = *(const int4*)kn;  kv1 = *(const int4*)(kn + 65536);
      vv0 = *(const int4*)vn;  vv1 = *(const int4*)(vn + 32 * MK);
    }

    #pragma unroll
    for (int ms = 0; ms < 2; ++ms) {
      // S'^T = K . Q^T (pre-scaled): lane holds S'[m = ms*64 + ...][q=ln]
      f32x16 s0 = {}, s1 = {};
      __builtin_amdgcn_s_setprio(1);
      #pragma unroll
      for (int kd = 0; kd < 4; ++kd) {
        int doff = (kd * 16 + hi * 8) ^ sw;
        bf16x8 kf0 = *(const bf16x8*)&Kl[cur][(ms * 64 + ln) * 64 + doff];
        bf16x8 kf1 = *(const bf16x8*)&Kl[cur][(ms * 64 + 32 + ln) * 64 + doff];
        bf16x8 qk = kd == 0 ? qf0 : kd == 1 ? qf1 : kd == 2 ? qf2 : qf3;
        s0 = __builtin_amdgcn_mfma_f32_32x32x16_bf16(kf0, qk, s0, 0, 0, 0);
        s1 = __builtin_amdgcn_mfma_f32_32x32x16_bf16(kf1, qk, s1, 0, 0, 0);
      }
      __builtin_amdgcn_s_setprio(0);

      float vm = fmaxf(max16(s0), max16(s1));

      // defer-max (T13), scaled domain: THR = 8*s2 = 1.4427
      if (!__all(vm - M_ <= 1.44269504f)) {
        float vm2 = fmaxf(vm, __shfl_xor(vm, 32));
        float mn = fmaxf(M_, vm2);
        float rc = fexp2(M_ - mn);
        M_ = mn;
        Lacc[0] *= rc;
        f32x2 rc2 = {rc, rc};
        f32x2* o0p = (f32x2*)&o0;
        f32x2* o1p = (f32x2*)&o1;
        #pragma unroll
        for (int i = 0; i < 8; ++i) { o0p[i] = pk_mul(o0p[i], rc2); }
        #pragma unroll
        for (int i = 0; i < 8; ++i) { o1p[i] = pk_mul(o1p[i], rc2); }
      }
      // P = exp2(S' - M_): packed bias-add then raw v_exp
      f32x2 nb2 = {-M_, -M_};
      f32x2* s0p = (f32x2*)&s0;
      f32x2* s1p = (f32x2*)&s1;
      #pragma unroll
      for (int i = 0; i < 8; ++i) s0p[i] = pk_add(s0p[i], nb2);
      #pragma unroll
      for (int i = 0; i < 8; ++i) s1p[i] = pk_add(s1p[i], nb2);
      #pragma unroll
      for (int i = 0; i < 16; ++i) s0[i] = fexp2(s0[i]);
      #pragma unroll
      for (int i = 0; i < 16; ++i) s1[i] = fexp2(s1[i]);

      // O^T += V^T . P^T ; Lacc += ones . P^T (collective row-sum)
      PV_CHUNK(s0, 0, 0, ms);
      PV_CHUNK(s0, 8, 1, ms);
      PV_CHUNK(s1, 0, 2, ms);
      PV_CHUNK(s1, 8, 3, ms);
    }

    if (it < 7) {   // write next tile into the other buffer, then ONE barrier
      *(int4*)&Kl[cur ^ 1][sdK] = kv0;  *(int4*)&Kl[cur ^ 1][sdK + 4096] = kv1;
      *(int4*)&Vl[cur ^ 1][sdV] = vv0;  *(int4*)&Vl[cur ^ 1][sdV + 4096] = vv1;
    }
    __syncthreads();
  }

  float inv = 1.0f / Lacc[0];   // complete sum (MFMA is lane-collective)
  u16* ob = (u16*)&O[(((size_t)(b * NQ + qrow)) * HEADS + h) * DHEAD];
  #pragma unroll
  for (int g = 0; g < 4; ++g) {
    union { u16 h4[4]; uint2 v; } r0, r1;
    #pragma unroll
    for (int s = 0; s < 4; ++s) {
      r0.h4[s] = f2bf(o0[4 * g + s] * inv);
      r1.h4[s] = f2bf(o1[4 * g + s] * inv);
    }
    *(uint2*)(ob + 8 * g + 4 * hi) = r0.v;
    *(uint2*)(ob + 32 + 8 * g + 4 * hi) = r1.v;
  }
}

// ---------------------------------------------------------------------------
extern "C" void kernel_launch(void* const* d_in, const int* in_sizes, int n_in,
                              void* d_out, int out_size, void* d_ws, size_t ws_size,
                              hipStream_t stream) {
  (void)in_sizes; (void)n_in; (void)out_size; (void)ws_size;
  const float* x   = (const float*)d_in[0];
  const float* ctx = (const float*)d_in[1];
  const float* Wq  = (const float*)d_in[2];
  const float* Wk  = (const float*)d_in[3];
  const float* Wv  = (const float*)d_in[4];
  const float* Wo  = (const float*)d_in[5];
  const float* bo  = (const float*)d_in[6];
  float* out = (float*)d_out;
  char* ws = (char*)d_ws;
  const size_t MB = 1u << 20;
  u16* xb  = (u16*)(ws);             // 16 MB: x bf16 [8192][1024]
  u16* cb  = (u16*)(ws + 16 * MB);   //  8 MB: ctx bf16 [4096][1024]
  u16* wt  = (u16*)(ws + 24 * MB);   //  8 MB: WqT,WkT,WvT,WoT bf16 [1024][1024] each
  u16* Qb  = (u16*)(ws + 32 * MB);   // 16 MB: Q bf16 [b,n,h,d] (pre-scaled by s2)
  u16* Kb  = (u16*)(ws + 48 * MB);   //  8 MB: K bf16 [b,m,h,d]
  u16* Vtb = (u16*)(ws + 56 * MB);   //  8 MB: Vt bf16 [b,h,d,m]
  u16* Ab  = (u16*)(ws + 64 * MB);   // 16 MB: attn out bf16 [b,n,h*64+d]

  k_pre<<<10240, 256, 0, stream>>>(x, ctx, Wq, Wk, Wv, Wo, xb, cb, wt);

  k_gemm_qkv<<<256, 512, 0, stream>>>(xb, cb, wt, Qb, Kb, Vtb);

  k_attn<<<512, 512, 0, stream>>>(Qb, Kb, Vtb, Ab);

  k_gemm_o<<<256, 512, 0, stream>>>(Ab, wt + 3145728, out, bo);
}